// Round 6
// baseline (46.081 us; speedup 1.0000x reference)
//
#include <hip/hip_runtime.h>
#include <math.h>

#define N_RAYS 86400
#define N_SAMP 287
#define GRP_W  16          // lanes per ray (4 rays per wave)
#define N_CHUNK 18         // ceil(287/16); even -> 9 pairs
#define LOG2E 1.4426950408889634f

// DPP row_shr:N prefix-shift within the 16-lane row; lanes below the row edge
// read `old` = 1.0f (multiplicative identity).
#define ROW_SHR_OLD1(x, N)                                                   \
    __int_as_float(__builtin_amdgcn_update_dpp(                              \
        0x3f800000 /*1.0f*/, __float_as_int(x), 0x110 | (N), 0xF, 0xF, false))

// ds_swizzle BitMode: new_lane = ((lane & and) | or) ^ xor  (per 32-lane half)
#define SWZ(x, pat) __int_as_float(__builtin_amdgcn_ds_swizzle(__float_as_int(x), (pat)))
#define SWZ_BCAST15 0x1F0   // lane 15 of each 16-group
#define SWZ_XOR(m)  (((m) << 10) | 0x1F)

__global__ __launch_bounds__(256) void nerf_depth_kernel(
    const float* __restrict__ rays_o,
    const float* __restrict__ rays_d,
    const float* __restrict__ voxel,
    float* __restrict__ depth_out,
    float stepf, float delta)
{
    const int lane = threadIdx.x & 63;
    const int sub  = lane & (GRP_W - 1);
    const int grp  = lane >> 4;
    const int wave = (blockIdx.x * blockDim.x + threadIdx.x) >> 6;
    const int ray  = wave * 4 + grp;         // 86400 = 4 * 21600, exact

    const float ox = rays_o[3*ray+0], oy = rays_o[3*ray+1], oz = rays_o[3*ray+2];
    const float dx = rays_d[3*ray+0], dy = rays_d[3*ray+1], dz = rays_d[3*ray+2];

    const float cx1 = 199.0f / 80.0f;                  const float cx0 = 40.0f * cx1;
    const float cz1 = 15.0f / (5.4f - (-1.0f));        const float cz0 = 1.0f * cz1;
    const float negdelta = -delta;

    float T = 1.0f;
    float depth_acc = 0.0f;

    // Per-chunk stage state kept in independent scalars so both chunks' loads
    // can be issued before either chunk's math consumes them.
    for (int c = 0; c < N_CHUNK; c += 2) {
        // ---------------- addresses + loads, chunk A (= c) ----------------
        const int   sA  = c * GRP_W + sub;
        const float zA  = __fmul_rn(stepf, (float)sA);
        const float pxA = __fadd_rn(ox, __fmul_rn(dx, zA));
        const float pyA = __fadd_rn(oy, __fmul_rn(dy, zA));
        const float pzA = __fadd_rn(oz, __fmul_rn(dz, zA));
        const bool inbA = !((fmaxf(fabsf(pxA), fabsf(pyA)) > 40.0f) |
                            (pzA < -1.0f) | (pzA > 5.4f)) && (sA < N_SAMP);
        float ixA = fminf(fmaxf(__builtin_fmaf(pxA, cx1, cx0), 0.0f), 199.0f);
        float iyA = fminf(fmaxf(__builtin_fmaf(pyA, cx1, cx0), 0.0f), 199.0f);
        float izA = fminf(fmaxf(__builtin_fmaf(pzA, cz1, cz0), 0.0f), 15.0f);
        int x0A = min((int)ixA, 198);
        int y0A = min((int)iyA, 198);
        int z0A = min((int)izA, 14);
        float fxA = ixA - (float)x0A;
        float fyA = iyA - (float)y0A;
        float fzA = izA - (float)z0A;
        const int cellA = (x0A * 200 + y0A) * 16 + z0A;
        float a000 = voxel[cellA];        float a001 = voxel[cellA + 1];
        float a010 = voxel[cellA + 16];   float a011 = voxel[cellA + 17];
        float a100 = voxel[cellA + 3200]; float a101 = voxel[cellA + 3201];
        float a110 = voxel[cellA + 3216]; float a111 = voxel[cellA + 3217];

        // ---------------- addresses + loads, chunk B (= c+1) ---------------
        const int   sB  = sA + GRP_W;
        const float zB  = __fmul_rn(stepf, (float)sB);
        const float pxB = __fadd_rn(ox, __fmul_rn(dx, zB));
        const float pyB = __fadd_rn(oy, __fmul_rn(dy, zB));
        const float pzB = __fadd_rn(oz, __fmul_rn(dz, zB));
        const bool inbB = !((fmaxf(fabsf(pxB), fabsf(pyB)) > 40.0f) |
                            (pzB < -1.0f) | (pzB > 5.4f)) && (sB < N_SAMP);
        float ixB = fminf(fmaxf(__builtin_fmaf(pxB, cx1, cx0), 0.0f), 199.0f);
        float iyB = fminf(fmaxf(__builtin_fmaf(pyB, cx1, cx0), 0.0f), 199.0f);
        float izB = fminf(fmaxf(__builtin_fmaf(pzB, cz1, cz0), 0.0f), 15.0f);
        int x0B = min((int)ixB, 198);
        int y0B = min((int)iyB, 198);
        int z0B = min((int)izB, 14);
        float fxB = ixB - (float)x0B;
        float fyB = iyB - (float)y0B;
        float fzB = izB - (float)z0B;
        const int cellB = (x0B * 200 + y0B) * 16 + z0B;
        float b000 = voxel[cellB];        float b001 = voxel[cellB + 1];
        float b010 = voxel[cellB + 16];   float b011 = voxel[cellB + 17];
        float b100 = voxel[cellB + 3200]; float b101 = voxel[cellB + 3201];
        float b110 = voxel[cellB + 3216]; float b111 = voxel[cellB + 3217];

        // pair-level exit condition, computed EARLY from pair-entry state:
        // - all 16 lanes of chunk A outside => (convex box, origin inside)
        //   everything from here on is outside
        // - T at pair entry below cutoff => residual depth <= 1e-6 * 57.4
        const unsigned long long bal = __ballot(inbA);
        const bool groupDead =
            (((unsigned)(bal >> (grp * GRP_W)) & 0xFFFFu) == 0u) | (T < 1e-6f);

        // ---------------- math, chunk A ----------------
        {
            float c00 = a000 + fzA * (a001 - a000);
            float c01 = a010 + fzA * (a011 - a010);
            float c10 = a100 + fzA * (a101 - a100);
            float c11 = a110 + fzA * (a111 - a110);
            float c0  = c00 + fyA * (c01 - c00);
            float c1  = c10 + fyA * (c11 - c10);
            float d   = c0  + fxA * (c1  - c0);
            float e2 = exp2f(d * LOG2E);
            float lg = __log2f(1.0f + e2);
            float alpha = 1.0f - exp2f(negdelta * lg);
            alpha = inbA ? alpha : 0.0f;
            float g = fmaxf(1.0f - alpha, 1e-10f);
            float P = g;
            P *= ROW_SHR_OLD1(P, 1);
            P *= ROW_SHR_OLD1(P, 2);
            P *= ROW_SHR_OLD1(P, 4);
            P *= ROW_SHR_OLD1(P, 8);
            float E = ROW_SHR_OLD1(P, 1);
            depth_acc = __builtin_fmaf(alpha * zA, T * E, depth_acc);
            T *= SWZ(P, SWZ_BCAST15);
        }

        // ---------------- math, chunk B ----------------
        {
            float c00 = b000 + fzB * (b001 - b000);
            float c01 = b010 + fzB * (b011 - b010);
            float c10 = b100 + fzB * (b101 - b100);
            float c11 = b110 + fzB * (b111 - b110);
            float c0  = c00 + fyB * (c01 - c00);
            float c1  = c10 + fyB * (c11 - c10);
            float d   = c0  + fxB * (c1  - c0);
            float e2 = exp2f(d * LOG2E);
            float lg = __log2f(1.0f + e2);
            float alpha = 1.0f - exp2f(negdelta * lg);
            alpha = inbB ? alpha : 0.0f;
            float g = fmaxf(1.0f - alpha, 1e-10f);
            float P = g;
            P *= ROW_SHR_OLD1(P, 1);
            P *= ROW_SHR_OLD1(P, 2);
            P *= ROW_SHR_OLD1(P, 4);
            P *= ROW_SHR_OLD1(P, 8);
            float E = ROW_SHR_OLD1(P, 1);
            depth_acc = __builtin_fmaf(alpha * zB, T * E, depth_acc);
            T *= SWZ(P, SWZ_BCAST15);
        }

        if (__all(groupDead)) break;
    }

    // sum the 16 per-lane partials
    depth_acc += SWZ(depth_acc, SWZ_XOR(1));
    depth_acc += SWZ(depth_acc, SWZ_XOR(2));
    depth_acc += SWZ(depth_acc, SWZ_XOR(4));
    depth_acc += SWZ(depth_acc, SWZ_XOR(8));
    if (sub == 0) depth_out[ray] = depth_acc;
}

extern "C" void kernel_launch(void* const* d_in, const int* in_sizes, int n_in,
                              void* d_out, int out_size, void* d_ws, size_t ws_size,
                              hipStream_t stream) {
    (void)in_sizes; (void)n_in; (void)d_ws; (void)ws_size; (void)out_size;
    const float* rays_o = (const float*)d_in[0];
    const float* rays_d = (const float*)d_in[1];
    const float* voxel  = (const float*)d_in[2];
    float* out = (float*)d_out;

    // numpy constant chain in float32: step == 0.2f
    float rngz  = 5.4f - (-1.0f);
    float prod  = (80.0f * 80.0f) * rngz;
    float ratio = prod / 640000.0f;
    float stepf = (float)(0.5 * pow((double)ratio, 1.0 / 3.0));
    float delta = stepf * 286.0f - stepf * 285.0f;

    // 4 rays/wave, 4 waves/block => 16 rays/block; 86400/16 = 5400 blocks
    nerf_depth_kernel<<<N_RAYS / 16, 256, 0, stream>>>(rays_o, rays_d, voxel, out, stepf, delta);
}

// Round 7
// 26.910 us; speedup vs baseline: 1.7124x; 1.7124x over previous
//
#include <hip/hip_runtime.h>
#include <math.h>

#define N_RAYS 86400
#define N_SAMP 287
#define GRP_W  16          // lanes per ray (4 rays per wave)
#define N_CHUNK 18         // ceil(287/16)
#define LOG2E 1.4426950408889634f

// DPP row_shr:N prefix-shift within the 16-lane row; lanes below the row edge
// read `old` = 1.0f (multiplicative identity).
#define ROW_SHR_OLD1(x, N)                                                   \
    __int_as_float(__builtin_amdgcn_update_dpp(                              \
        0x3f800000 /*1.0f*/, __float_as_int(x), 0x110 | (N), 0xF, 0xF, false))

// ds_swizzle BitMode: new_lane = ((lane & and) | or) ^ xor  (per 32-lane half)
#define SWZ(x, pat) __int_as_float(__builtin_amdgcn_ds_swizzle(__float_as_int(x), (pat)))
#define SWZ_BCAST15 0x1F0   // lane 15 of each 16-group
#define SWZ_XOR(m)  (((m) << 10) | 0x1F)

struct F2 { float lo, hi; };   // 8-byte z-pair, loaded with one dwordx2

__global__ __launch_bounds__(256) void nerf_depth_kernel(
    const float* __restrict__ rays_o,
    const float* __restrict__ rays_d,
    const float* __restrict__ voxel,
    float* __restrict__ depth_out,
    float stepf, float delta)
{
    const int lane = threadIdx.x & 63;
    const int sub  = lane & (GRP_W - 1);
    const int grp  = lane >> 4;
    const int wave = (blockIdx.x * blockDim.x + threadIdx.x) >> 6;
    const int ray  = wave * 4 + grp;         // 86400 = 4 * 21600, exact

    const float ox = rays_o[3*ray+0], oy = rays_o[3*ray+1], oz = rays_o[3*ray+2];
    const float dx = rays_d[3*ray+0], dy = rays_d[3*ray+1], dz = rays_d[3*ray+2];

    const float cx1 = 199.0f / 80.0f;                  const float cx0 = 40.0f * cx1;
    const float cz1 = 15.0f / (5.4f - (-1.0f));        const float cz0 = 1.0f * cz1;
    const float negdelta = -delta;

    float T = 1.0f;          // group-uniform running transmittance
    float depth_acc = 0.0f;  // per-lane partial depth
    bool  done = false;      // group-uniform

    for (int c = 0; c < N_CHUNK; ++c) {
        const int  s     = c * GRP_W + sub;
        const bool valid = (s < N_SAMP);
        const float z  = __fmul_rn(stepf, (float)s);
        // mask must stay bit-exact vs numpy: separate mul + add, strict compares
        const float px = __fadd_rn(ox, __fmul_rn(dx, z));
        const float py = __fadd_rn(oy, __fmul_rn(dy, z));
        const float pz = __fadd_rn(oz, __fmul_rn(dz, z));
        const bool inside = !((fmaxf(fabsf(px), fabsf(py)) > 40.0f) |
                              (pz < -1.0f) | (pz > 5.4f));
        const bool inb = (!done) && valid && inside;

        // group termination: ray starts inside a convex box, so an all-outside
        // chunk means outside forever
        const unsigned long long bal = __ballot(inb);
        if (((unsigned)(bal >> (grp * GRP_W)) & 0xFFFFu) == 0u) done = true;
        if (__all(done)) break;

        float alpha = 0.0f, az = 0.0f;
        if (inb) {
            float ix = fminf(fmaxf(__builtin_fmaf(px, cx1, cx0), 0.0f), 199.0f);
            float iy = fminf(fmaxf(__builtin_fmaf(py, cx1, cx0), 0.0f), 199.0f);
            float iz = fminf(fmaxf(__builtin_fmaf(pz, cz1, cz0), 0.0f), 15.0f);
            int x0 = min((int)ix, 198);
            int y0 = min((int)iy, 198);
            int z0 = min((int)iz, 14);
            float fx = ix - (float)x0;
            float fy = iy - (float)y0;
            float fz = iz - (float)z0;
            // 8 corners via 4 8-byte z-pair loads (each pair is within one
            // 64B line: a 16-float z-column never straddles a line)
            const float* p00 = voxel + ((x0 * 200 + y0) * 16 + z0);
            F2 q00, q01, q10, q11;
            __builtin_memcpy(&q00, p00,        8);   // (x0,   y0  )
            __builtin_memcpy(&q01, p00 + 16,   8);   // (x0,   y0+1)
            __builtin_memcpy(&q10, p00 + 3200, 8);   // (x0+1, y0  )
            __builtin_memcpy(&q11, p00 + 3216, 8);   // (x0+1, y0+1)
            float c00 = q00.lo + fz * (q00.hi - q00.lo);
            float c01 = q01.lo + fz * (q01.hi - q01.lo);
            float c10 = q10.lo + fz * (q10.hi - q10.lo);
            float c11 = q11.lo + fz * (q11.hi - q11.lo);
            float c0  = c00 + fy * (c01 - c00);
            float c1  = c10 + fy * (c11 - c10);
            float d   = c0  + fx * (c1  - c0);
            // alpha = 1 - exp(-delta*softplus(d)) = 1 - 2^(-delta*log2(1+e^d))
            float e2 = exp2f(d * LOG2E);
            float lg = __log2f(1.0f + e2);
            alpha = 1.0f - exp2f(negdelta * lg);
            az = alpha * z;
        }

        float g = fmaxf(1.0f - alpha, 1e-10f);

        // 16-lane inclusive prefix product via DPP row_shr
        float P = g;
        P *= ROW_SHR_OLD1(P, 1);
        P *= ROW_SHR_OLD1(P, 2);
        P *= ROW_SHR_OLD1(P, 4);
        P *= ROW_SHR_OLD1(P, 8);
        float E = ROW_SHR_OLD1(P, 1);      // exclusive prefix (lane0 -> 1.0)

        depth_acc = __builtin_fmaf(az, T * E, depth_acc);
        T *= SWZ(P, SWZ_BCAST15);          // chunk product -> all 16 lanes

        if (T < 1e-6f) done = true;        // residual depth <= 1e-6 * 57.4
    }

    // sum the 16 per-lane partials
    depth_acc += SWZ(depth_acc, SWZ_XOR(1));
    depth_acc += SWZ(depth_acc, SWZ_XOR(2));
    depth_acc += SWZ(depth_acc, SWZ_XOR(4));
    depth_acc += SWZ(depth_acc, SWZ_XOR(8));
    if (sub == 0) depth_out[ray] = depth_acc;
}

extern "C" void kernel_launch(void* const* d_in, const int* in_sizes, int n_in,
                              void* d_out, int out_size, void* d_ws, size_t ws_size,
                              hipStream_t stream) {
    (void)in_sizes; (void)n_in; (void)d_ws; (void)ws_size; (void)out_size;
    const float* rays_o = (const float*)d_in[0];
    const float* rays_d = (const float*)d_in[1];
    const float* voxel  = (const float*)d_in[2];
    float* out = (float*)d_out;

    // numpy constant chain in float32: step == 0.2f
    float rngz  = 5.4f - (-1.0f);
    float prod  = (80.0f * 80.0f) * rngz;
    float ratio = prod / 640000.0f;
    float stepf = (float)(0.5 * pow((double)ratio, 1.0 / 3.0));
    float delta = stepf * 286.0f - stepf * 285.0f;

    // 4 rays/wave, 4 waves/block => 16 rays/block; 86400/16 = 5400 blocks
    nerf_depth_kernel<<<N_RAYS / 16, 256, 0, stream>>>(rays_o, rays_d, voxel, out, stepf, delta);
}